// Round 6
// baseline (550.989 us; speedup 1.0000x reference)
//
#include <hip/hip_runtime.h>

typedef unsigned short u16;
typedef unsigned int   u32;

#define NN 16384
#define BN 524288      /* B*N = 32*16384 */
#define LN_EPS 1e-5f

typedef __attribute__((ext_vector_type(8))) short bf16x8;
typedef __attribute__((ext_vector_type(4))) float f32x4;
#define MFMA(a,b,c) __builtin_amdgcn_mfma_f32_16x16x32_bf16(a,b,c,0,0,0)

// ---------------- helpers ----------------
__device__ __forceinline__ float bf2f(u16 h){
  union { u32 u; float f; } c; c.u = ((u32)h) << 16; return c.f;
}
__device__ __forceinline__ u16 f2bf(float f){
  union { float f; u32 u; } c; c.f = f;
  u32 r = (c.u + 0x7fffu + ((c.u >> 16) & 1u)) >> 16;   // RNE
  return (u16)r;
}
__device__ __forceinline__ u32 pack2(float a, float b){
  return (u32)f2bf(a) | ((u32)f2bf(b) << 16);
}
__device__ __forceinline__ void unpack8(uint4 v, float* o){
  o[0]=bf2f((u16)(v.x&0xffffu)); o[1]=bf2f((u16)(v.x>>16));
  o[2]=bf2f((u16)(v.y&0xffffu)); o[3]=bf2f((u16)(v.y>>16));
  o[4]=bf2f((u16)(v.z&0xffffu)); o[5]=bf2f((u16)(v.z>>16));
  o[6]=bf2f((u16)(v.w&0xffffu)); o[7]=bf2f((u16)(v.w>>16));
}
__device__ __forceinline__ float ldin(const void* p, int i, int isbf){
  return isbf ? bf2f(((const u16*)p)[i]) : ((const float*)p)[i];
}

// ---------------- fp32 weight arena offsets (floats) ----------------
enum {
  O_LNING=0, O_LNINB=64, O_LNSG=128, O_LNSB=192, O_LNMG=256, O_LNMB=320,
  O_WQ=384, O_WK=4480, O_WV=8576,
  O_WIH=12672, O_WHH=24960, O_BIH=37248, O_BHH=37440,
  O_MLPW1=37632, O_MLPB1=45824, O_MLPW2=45952, O_MLPB2=54144,
  O_PAW=54208, O_PAB=54336,
  O_PEG=54400, O_PEB=54464, O_PEW1=54528, O_PEB1=62720, O_PEW2=62848, O_PEB2=71040,
  W_TOTAL=71104
};
__device__ const int g_woff[25] = {O_LNING,O_LNINB,O_LNSG,O_LNSB,O_LNMG,O_LNMB,
  O_WQ,O_WK,O_WV,O_WIH,O_WHH,O_BIH,O_BHH,O_MLPW1,O_MLPB1,O_MLPW2,O_MLPB2,
  O_PAW,O_PAB,O_PEG,O_PEB,O_PEW1,O_PEB1,O_PEW2,O_PEB2};
__device__ const int g_wsz[25]  = {64,64,64,64,64,64,4096,4096,4096,12288,12288,
  192,192,8192,128,8192,64,128,64,64,64,8192,128,8192,64};

struct WP { const void* p[25]; };

// ---------------- kernel: detect input dtype ----------------
__global__ void kdetect_kernel(const u16* __restrict__ inp, int* __restrict__ flag){
  if (threadIdx.x == 0 && blockIdx.x == 0){
    int votes = 0;
    for (int i = 0; i < 64; i++){
      u16 h = inp[2*i];
      int e = (h >> 7) & 0xff;
      int m = h & 0x7f;
      if ((e == 0 && m == 0) || (e >= 100 && e <= 144)) votes++;
    }
    flag[0] = (votes >= 48) ? 1 : 0;   // 1 = bf16, 0 = fp32
  }
}

// ---------------- kernel: weight convert (->fp32 arena) + state init ----------------
__global__ __launch_bounds__(256) void kw_kernel(WP wp, float* __restrict__ w,
                                                 float* __restrict__ state,
                                                 const void* __restrict__ slots,
                                                 const int* __restrict__ flag){
  int isbf = flag[0];
  int blk = blockIdx.x;
  if (blk < 25){
    const void* src = wp.p[blk];
    int off = g_woff[blk], sz = g_wsz[blk];
    for (int i = threadIdx.x; i < sz; i += 256)
      w[off + i] = ldin(src, i, isbf);
  } else {
    for (int i = threadIdx.x; i < 512; i += 256){
      float sv = ldin(slots, i, isbf);
      for (int b = 0; b < 32; b++) state[b*512 + i] = sv;
    }
  }
}

// ---------------- kernel: pack B-fragment buffers (bf16, MFMA B-layout) ----------------
__global__ __launch_bounds__(256) void kpack_kernel(WP wp, u16* __restrict__ fkv,
                                                    u16* __restrict__ f1,
                                                    u16* __restrict__ f2,
                                                    const int* __restrict__ flag){
  int isbf = flag[0];
  int blk = blockIdx.x;
  const void* pWk = wp.p[7];  const void* pWv = wp.p[8];
  const void* pW1 = wp.p[21]; const void* pW2 = wp.p[23];
  for (int e = threadIdx.x; e < 8192; e += 256){
    int j = e & 7, lane = (e >> 3) & 63, frag = e >> 9;
    int qd = lane >> 4, l15 = lane & 15;
    if (blk == 0){           // [Wk|Wv]: K=64, N=128, frag = nt*2 + ks
      int nt = frag >> 1, ks = frag & 1;
      int k = ks*32 + qd*8 + j, n = nt*16 + l15;
      float v = (n < 64) ? ldin(pWk, k*64 + n, isbf) : ldin(pWv, k*64 + (n-64), isbf);
      fkv[e] = f2bf(v);
    } else if (blk == 1){    // pe_W1: K=64, N=128
      int nt = frag >> 1, ks = frag & 1;
      int k = ks*32 + qd*8 + j, n = nt*16 + l15;
      f1[e] = f2bf(ldin(pW1, k*128 + n, isbf));
    } else {                 // pe_W2: K=128, N=64, frag = nt*4 + s
      int nt = frag >> 2, s = frag & 3;
      int k = s*32 + qd*8 + j, n = nt*16 + l15;
      f2[e] = f2bf(ldin(pW2, k*64 + n, isbf));
    }
  }
}

// ============== FUSED kernel: LN + [k|v] GEMM + pos-enc MLP (64 rows/block) ==========
// Outputs: kbuf row-major (n x 64), vtg d-major (VT[b][d][n]).
#define KVS 136
__global__ __launch_bounds__(256) void k0_kernel(const void* __restrict__ inpv,
                                                 const float* __restrict__ w,
                                                 const u16* __restrict__ fkv,
                                                 const u16* __restrict__ f1,
                                                 const u16* __restrict__ f2,
                                                 u16* __restrict__ kbuf,
                                                 u16* __restrict__ vtg,
                                                 const int* __restrict__ flag){
  __shared__ __align__(16) u16 shA[5120];     // T1(64x72) -> Hw(4x32x40) -> Vt(64x72)
  __shared__ __align__(16) u16 shB[128*72];   // KV(64xKVS) -> T2(128x72) -> Kout(64x72)
  __shared__ float gbuf[128];
  int isbf = flag[0];
  int t = threadIdx.x;
  size_t row0 = (size_t)blockIdx.x * 64;
  int lane = t & 63, wid = t >> 6, qd = lane >> 4, l15 = lane & 15;

  // ---- P1: LN(feats), 4 threads per row (all 256 threads active) ----
  {
    int rr = t >> 2, part = t & 3;
    size_t row = row0 + rr;
    float x[16];
    if (isbf){
      const u32* up = (const u32*)((const u16*)inpv + row*66 + part*16);
#pragma unroll
      for (int c = 0; c < 8; c++){
        u32 v = up[c];
        x[2*c] = bf2f((u16)(v & 0xffffu)); x[2*c+1] = bf2f((u16)(v >> 16));
      }
      if (part == 3){
        u32 gv = *(const u32*)((const u16*)inpv + row*66 + 64);
        gbuf[2*rr] = bf2f((u16)(gv & 0xffffu)); gbuf[2*rr+1] = bf2f((u16)(gv >> 16));
      }
    } else {
      const float2* fp = (const float2*)((const float*)inpv + row*66 + part*16);
#pragma unroll
      for (int c = 0; c < 8; c++){ float2 v = fp[c]; x[2*c] = v.x; x[2*c+1] = v.y; }
      if (part == 3){
        float2 gv = *(const float2*)((const float*)inpv + row*66 + 64);
        gbuf[2*rr] = gv.x; gbuf[2*rr+1] = gv.y;
      }
    }
    float s1 = 0.f, s2 = 0.f;
#pragma unroll
    for (int i = 0; i < 16; i++){ s1 += x[i]; s2 += x[i]*x[i]; }
    s1 += __shfl_xor(s1, 1, 64); s1 += __shfl_xor(s1, 2, 64);
    s2 += __shfl_xor(s2, 1, 64); s2 += __shfl_xor(s2, 2, 64);
    float mu = s1*(1.f/64.f);
    float rs = rsqrtf(s2*(1.f/64.f) - mu*mu + LN_EPS);
    u32 pk[8];
#pragma unroll
    for (int c = 0; c < 8; c++){
      int i0 = part*16 + 2*c;
      float a = (x[2*c]  -mu)*rs*w[O_LNING+i0]   + w[O_LNINB+i0];
      float b = (x[2*c+1]-mu)*rs*w[O_LNING+i0+1] + w[O_LNINB+i0+1];
      pk[c] = pack2(a, b);
    }
    *(uint4*)&shA[rr*72 + part*16]     = *(uint4*)&pk[0];
    *(uint4*)&shA[rr*72 + part*16 + 8] = *(uint4*)&pk[4];
  }
  __syncthreads();

  // ---- P2: [k|v] = T1 @ fkv -> KV in shB ----
  {
    bf16x8 af[2];
#pragma unroll
    for (int ks = 0; ks < 2; ks++)
      af[ks] = *(const bf16x8*)&shA[(wid*16 + l15)*72 + ks*32 + qd*8];
#pragma unroll
    for (int nt = 0; nt < 8; nt++){
      bf16x8 b0 = *(const bf16x8*)(fkv + ((size_t)(nt*2+0)*64 + lane)*8);
      bf16x8 b1 = *(const bf16x8*)(fkv + ((size_t)(nt*2+1)*64 + lane)*8);
      f32x4 acc = {0.f,0.f,0.f,0.f};
      acc = MFMA(af[0], b0, acc);
      acc = MFMA(af[1], b1, acc);
      int rb = wid*16 + qd*4;
#pragma unroll
      for (int r = 0; r < 4; r++) shB[(rb+r)*KVS + nt*16 + l15] = f2bf(acc[r]);
    }
  }
  __syncthreads();

  // ---- P3: pos-enc LN, 2 threads per virtual row (128 vrows: 0-63 k, 64-127 v) ----
  float tv[32];
  int vr = t >> 1, half = t & 1;
  {
    int phys = vr & 63, isv = vr >> 6;
    float g0 = gbuf[2*phys], g1 = gbuf[2*phys+1];
    const uint4* rp = (const uint4*)&shB[phys*KVS + isv*64 + half*32];
#pragma unroll
    for (int c = 0; c < 4; c++){ uint4 q4 = rp[c]; unpack8(q4, &tv[c*8]); }
#pragma unroll
    for (int i = 0; i < 32; i++){
      int gi = half*32 + i;
      tv[i] += g0*w[O_PAW+gi] + g1*w[O_PAW+64+gi] + w[O_PAB+gi];
    }
    float s1 = 0.f, s2 = 0.f;
#pragma unroll
    for (int i = 0; i < 32; i++){ s1 += tv[i]; s2 += tv[i]*tv[i]; }
    s1 += __shfl_xor(s1, 1, 64);
    s2 += __shfl_xor(s2, 1, 64);
    float mu = s1*(1.f/64.f);
    float rs = rsqrtf(s2*(1.f/64.f) - mu*mu + LN_EPS);
#pragma unroll
    for (int i = 0; i < 32; i++){
      int gi = half*32 + i;
      tv[i] = (tv[i]-mu)*rs*w[O_PEG+gi] + w[O_PEB+gi];
    }
  }
  __syncthreads();         // KV reads done; shB reusable as T2
  {
    u32 pk[4];
#pragma unroll
    for (int c = 0; c < 4; c++){
      pk[0] = pack2(tv[8*c],  tv[8*c+1]); pk[1] = pack2(tv[8*c+2], tv[8*c+3]);
      pk[2] = pack2(tv[8*c+4],tv[8*c+5]); pk[3] = pack2(tv[8*c+6], tv[8*c+7]);
      *(uint4*)&shB[vr*72 + half*32 + c*8] = *(uint4*)pk;
    }
  }
  __syncthreads();

  // ---- P4: MLP; wave covers 32 virtual rows ----
  f32x4 out[2][4];
  {
    u16* Hw = shA + wid*1280;                  // 32 rows x 40 u16
    bf16x8 af[2][2];
#pragma unroll
    for (int mt = 0; mt < 2; mt++)
#pragma unroll
      for (int ks = 0; ks < 2; ks++)
        af[mt][ks] = *(const bf16x8*)&shB[(wid*32 + mt*16 + l15)*72 + ks*32 + qd*8];
#pragma unroll
    for (int mt = 0; mt < 2; mt++)
#pragma unroll
      for (int nt = 0; nt < 4; nt++) out[mt][nt] = (f32x4){0.f,0.f,0.f,0.f};

#pragma unroll
    for (int s = 0; s < 4; s++){
#pragma unroll
      for (int e = 0; e < 2; e++){
        int nn = s*2 + e;
        bf16x8 b0 = *(const bf16x8*)(f1 + ((size_t)(nn*2+0)*64 + lane)*8);
        bf16x8 b1 = *(const bf16x8*)(f1 + ((size_t)(nn*2+1)*64 + lane)*8);
        float bias1 = w[O_PEB1 + nn*16 + l15];
#pragma unroll
        for (int mt = 0; mt < 2; mt++){
          f32x4 h = {0.f,0.f,0.f,0.f};
          h = MFMA(af[mt][0], b0, h);
          h = MFMA(af[mt][1], b1, h);
#pragma unroll
          for (int r = 0; r < 4; r++)
            Hw[(mt*16 + qd*4 + r)*40 + e*16 + l15] = f2bf(fmaxf(h[r] + bias1, 0.f));
        }
      }
      bf16x8 a2[2];
#pragma unroll
      for (int mt = 0; mt < 2; mt++)
        a2[mt] = *(const bf16x8*)&Hw[(mt*16 + l15)*40 + qd*8];   // same-wave RAW
#pragma unroll
      for (int nt = 0; nt < 4; nt++){
        bf16x8 bw = *(const bf16x8*)(f2 + ((size_t)(nt*4 + s)*64 + lane)*8);
#pragma unroll
        for (int mt = 0; mt < 2; mt++)
          out[mt][nt] = MFMA(a2[mt], bw, out[mt][nt]);
      }
    }
  }
  __syncthreads();   // all Hw(shA) + T2(shB) reads done; both reusable

  // ---- epilogue: k rows -> shB (row-major); v rows -> shA (transposed Vt) ----
  if (wid < 2){
#pragma unroll
    for (int nt = 0; nt < 4; nt++){
      float b2v = w[O_PEB2 + nt*16 + l15];
#pragma unroll
      for (int mt = 0; mt < 2; mt++){
        int rb = wid*32 + mt*16 + qd*4;
#pragma unroll
        for (int r = 0; r < 4; r++)
          shB[(rb+r)*72 + nt*16 + l15] = f2bf(out[mt][nt][r] + b2v);
      }
    }
  } else {
#pragma unroll
    for (int nt = 0; nt < 4; nt++){
      float b2v = w[O_PEB2 + nt*16 + l15];
#pragma unroll
      for (int mt = 0; mt < 2; mt++){
        int vrr = (wid-2)*32 + mt*16 + qd*4;
#pragma unroll
        for (int r = 0; r < 4; r++)
          shA[(nt*16 + l15)*72 + vrr + r] = f2bf(out[mt][nt][r] + b2v);
      }
    }
  }
  __syncthreads();

  // ---- vectorized copies: k (shB) -> kbuf ; Vt (shA) -> vtg [b][d][n] ----
  {
    int rr2 = t >> 2, c = t & 3;
    uint4 k0v = *(const uint4*)&shB[rr2*72 + c*16];
    uint4 k1v = *(const uint4*)&shB[rr2*72 + c*16 + 8];
    u16* kd = kbuf + (row0 + rr2)*64 + c*16;
    *(uint4*)kd = k0v;
    *(uint4*)(kd + 8) = k1v;

    int b  = (int)(row0 >> 14);
    int nl = (int)(row0 & 16383);
    uint4 v0 = *(const uint4*)&shA[rr2*72 + c*16];
    uint4 v1 = *(const uint4*)&shA[rr2*72 + c*16 + 8];
    u16* dst = vtg + (size_t)b*1048576 + (size_t)rr2*NN + nl + c*16;
    *(uint4*)dst = v0;
    *(uint4*)(dst + 8) = v1;
  }
}

// ---------------- kernel: initial q = 0.125*LN(state)@Wq -> qf (MFMA B-frag) -----
__global__ __launch_bounds__(512) void b1_kernel(const float* __restrict__ w,
                                                 const float* __restrict__ state,
                                                 u16* __restrict__ qf){
  __shared__ float qrow[8*64];
  int b = blockIdx.x, t = threadIdx.x;
  int s = t >> 6, lane = t & 63;
  float xv = state[(b*8+s)*64 + lane];
  float sum = xv;
#pragma unroll
  for (int off = 32; off; off >>= 1) sum += __shfl_xor(sum, off, 64);
  float mu = sum * (1.f/64.f);
  float xc = xv - mu;
  float ss = xc*xc;
#pragma unroll
  for (int off = 32; off; off >>= 1) ss += __shfl_xor(ss, off, 64);
  float rs = rsqrtf(ss*(1.f/64.f) + LN_EPS);
  float xln = xc*rs*w[O_LNSG+lane] + w[O_LNSB+lane];
  float acc = 0.f;
#pragma unroll
  for (int i = 0; i < 64; i++){
    float xi = __shfl(xln, i, 64);
    acc += xi * w[O_WQ + i*64 + lane];
  }
  qrow[s*64 + lane] = acc * 0.125f;          // fold D^-0.5
  __syncthreads();
  if (t < 128){
    int ks = t >> 6, ln = t & 63, ql = ln & 15, qq = ln >> 4;
    u32 pk[4];
#pragma unroll
    for (int jp = 0; jp < 4; jp++){
      float v0 = (ql < 8) ? qrow[ql*64 + ks*32 + qq*8 + 2*jp]     : 0.f;
      float v1 = (ql < 8) ? qrow[ql*64 + ks*32 + qq*8 + 2*jp + 1] : 0.f;
      pk[jp] = pack2(v0, v1);
    }
    *(uint4*)(qf + ((size_t)(b*2+ks)*64 + ln)*8) = *(uint4*)pk;
  }
}

// ---------------- kernel: attention (MFMA QK + softmax + MFMA PV), 512 n/block ----
#define PMS 520
__global__ __launch_bounds__(256) void b2_kernel(const u16* __restrict__ kbuf,
                                                 const u16* __restrict__ vtg,
                                                 const u16* __restrict__ qf,
                                                 float* __restrict__ pupd,
                                                 float* __restrict__ psums){
  __shared__ __align__(16) u16 pm[8*PMS];        // P, bf16 (8 slot rows, padded)
  int t = threadIdx.x, lane = t & 63, wid = t >> 6, l15 = lane & 15, quad = lane >> 4;
  int b = blockIdx.x >> 5, chunk = blockIdx.x & 31;
  size_t gn0 = (size_t)b*NN + (size_t)chunk*512;

  bf16x8 q0 = *(const bf16x8*)(qf + ((size_t)(b*2+0)*64 + lane)*8);
  bf16x8 q1 = *(const bf16x8*)(qf + ((size_t)(b*2+1)*64 + lane)*8);

  float psum = 0.f;
  int wbase = wid*128;
#pragma unroll
  for (int mt = 0; mt < 8; mt++){
    const u16* kp = kbuf + (gn0 + wbase + mt*16 + l15)*64;
    bf16x8 a0 = *(const bf16x8*)(kp + quad*8);
    bf16x8 a1 = *(const bf16x8*)(kp + 32 + quad*8);
    f32x4 dg = {0.f,0.f,0.f,0.f};
    dg = MFMA(a0, q0, dg);
    dg = MFMA(a1, q1, dg);
#pragma unroll
    for (int r = 0; r < 4; r++){
      float lg = fminf(dg[r], 40.f);           // softmax w/o max-sub (clamped)
      float ex = __expf(lg);
      float es = ex;
      es += __shfl_xor(es, 1, 64);
      es += __shfl_xor(es, 2, 64);
      es += __shfl_xor(es, 4, 64);
      float p = __fdividef(ex, es) + 1e-8f;
      psum += p;
      if (l15 < 8){
        int n = wbase + mt*16 + quad*4 + r;
        pm[l15*PMS + n] = f2bf(p);
      }
    }
  }
  psum += __shfl_xor(psum, 16, 64);
  psum += __shfl_xor(psum, 32, 64);
  if (quad == 0 && l15 < 8)
    psums[(size_t)((b*32+chunk)*4 + wid)*8 + l15] = psum;
  __syncthreads();

  // PV swapped: A = VT rows (m=d), B = P^T (col=s; cols 8..15 garbage, ignored)
  f32x4 acc = {0.f,0.f,0.f,0.f};
  const u16* vp  = vtg + (size_t)b*1048576 + (size_t)(wid*16 + l15)*NN
                       + (size_t)chunk*512 + quad*8;
  const u16* pmr = pm + (l15 & 7)*PMS + quad*8;
#pragma unroll
  for (int ks = 0; ks < 16; ks++){
    bf16x8 va = *(const bf16x8*)(vp + ks*32);
    bf16x8 pb = *(const bf16x8*)(pmr + ks*32);
    acc = MFMA(va, pb, acc);
  }
  if (l15 < 8){
    float4 st = { acc[0], acc[1], acc[2], acc[3] };   // 4 consecutive d
    *(float4*)(pupd + (size_t)(b*32+chunk)*512 + l15*64 + wid*16 + quad*4) = st;
  }
}

// ------- kernel: partial-reduce + GRU + MLP + next-q, one block per (b,s) --------
__global__ __launch_bounds__(192) void b3q_kernel(const float* __restrict__ w,
                                                  float* __restrict__ state,
                                                  const float* __restrict__ pupd,
                                                  const float* __restrict__ psums,
                                                  u16* __restrict__ qf){
  __shared__ float uL[64], pv[64], hL[64], hln[64], gx[192], gh[192], hid[128], red[128], qs[64];
  __shared__ float ssum;
  int bs = blockIdx.x, b = bs >> 3, s = bs & 7, t = threadIdx.x;

  if (t < 64){
    float a = 0.f;
    const float* pp = pupd + (size_t)b*32*512 + s*64 + t;
#pragma unroll 4
    for (int c = 0; c < 32; c++) a += pp[(size_t)c*512];
    uL[t] = a;
    pv[t] = state[(b*8+s)*64 + t];
  } else {
    int i = t - 64;    // 128 (chunk,wave) partial sums
    red[i] = psums[(size_t)(b*128 + i)*8 + s];
  }
  __syncthreads();
  if (t == 0){ float a = 0.f; for (int i = 0; i < 128; i++) a += red[i]; ssum = a; }
  __syncthreads();

  { // gx, gh (j = t, 192 threads); fold 1/ssum into gx linear term
    float inv = 1.f/ssum;
    int j = t;
    float x0=0.f,x1=0.f,x2=0.f,x3=0.f, y0=0.f,y1=0.f,y2=0.f,y3=0.f;
#pragma unroll 4
    for (int d = 0; d < 64; d += 4){
      x0 += uL[d]  *w[O_WIH + (d)*192 + j];   y0 += pv[d]  *w[O_WHH + (d)*192 + j];
      x1 += uL[d+1]*w[O_WIH + (d+1)*192 + j]; y1 += pv[d+1]*w[O_WHH + (d+1)*192 + j];
      x2 += uL[d+2]*w[O_WIH + (d+2)*192 + j]; y2 += pv[d+2]*w[O_WHH + (d+2)*192 + j];
      x3 += uL[d+3]*w[O_WIH + (d+3)*192 + j]; y3 += pv[d+3]*w[O_WHH + (d+3)*192 + j];
    }
    gx[j] = w[O_BIH + j] + (x0+x1+x2+x3)*inv;
    gh[j] = w[O_BHH + j] + (y0+y1+y2+y3);
  }
  __syncthreads();

  if (t < 64){
    int d = t;
    float r = 1.f/(1.f + expf(-(gx[d]      + gh[d])));
    float z = 1.f/(1.f + expf(-(gx[64+d]   + gh[64+d])));
    float nv = tanhf(gx[128+d] + r*gh[128+d]);
    hL[d] = (1.f - z)*nv + z*pv[d];
  }
  __syncthreads();

  if (t < 64){
    float h = hL[t];
    float sum = h;
#pragma unroll
    for (int off = 32; off; off >>= 1) sum += __shfl_xor(sum, off, 64);
    float mu = sum * (1.f/64.f);
    float xc = h - mu;
    float ss2 = xc*xc;
#pragma unroll
    for (int off = 32; off; off >>= 1) ss2 += __shfl_xor(ss2, off, 64);
    float rs = rsqrtf(ss2*(1.f/64.f) + LN_EPS);
    hln[t] = xc*rs*w[O_LNMG+t] + w[O_LNMB+t];
  }
  __syncthreads();

  if (t < 128){
    int j = t;
    float a0=0.f,a1=0.f,a2v=0.f,a3=0.f;
#pragma unroll 4
    for (int d = 0; d < 64; d += 4){
      a0  += hln[d]  *w[O_MLPW1 + (d)*128 + j];
      a1  += hln[d+1]*w[O_MLPW1 + (d+1)*128 + j];
      a2v += hln[d+2]*w[O_MLPW1 + (d+2)*128 + j];
      a3  += hln[d+3]*w[O_MLPW1 + (d+3)*128 + j];
    }
    hid[j] = fmaxf(a0+a1+a2v+a3 + w[O_MLPB1 + j], 0.f);
  }
  __syncthreads();

  if (t < 64){
    int d = t;
    float o0=0.f,o1=0.f,o2=0.f,o3=0.f;
#pragma unroll 4
    for (int j = 0; j < 128; j += 4){
      o0 += hid[j]  *w[O_MLPW2 + (j)*64 + d];
      o1 += hid[j+1]*w[O_MLPW2 + (j+1)*64 + d];
      o2 += hid[j+2]*w[O_MLPW2 + (j+2)*64 + d];
      o3 += hid[j+3]*w[O_MLPW2 + (j+3)*64 + d];
    }
    float sv = hL[d] + o0+o1+o2+o3 + w[O_MLPB2 + d];
    state[(b*8+s)*64 + d] = sv;

    // ---- next iteration's q row for this (b,s): 0.125 * LN(sv) @ Wq ----
    float sum = sv;
#pragma unroll
    for (int off = 32; off; off >>= 1) sum += __shfl_xor(sum, off, 64);
    float mu = sum * (1.f/64.f);
    float xc = sv - mu;
    float ss2 = xc*xc;
#pragma unroll
    for (int off = 32; off; off >>= 1) ss2 += __shfl_xor(ss2, off, 64);
    float rs = rsqrtf(ss2*(1.f/64.f) + LN_EPS);
    float xln = xc*rs*w[O_LNSG+d] + w[O_LNSB+d];
    float q = 0.f;
#pragma unroll
    for (int i = 0; i < 64; i++){
      float xi = __shfl(xln, i, 64);
      q += xi * w[O_WQ + i*64 + d];
    }
    qs[d] = q * 0.125f;
  }
  __syncthreads();

  if (t < 32){   // scatter this s's slice of the qf B-frag pack
    int ks = t >> 4, qq = (t >> 2) & 3, jp = t & 3;
    u32 v = pack2(qs[ks*32 + qq*8 + 2*jp], qs[ks*32 + qq*8 + 2*jp + 1]);
    *(u32*)(qf + ((size_t)((b*2+ks)*64) + qq*16 + s)*8 + jp*2) = v;
  }
}

// ---------------- kernel: state (fp32) -> out (bf16 or fp32 per flag) ----------------
__global__ __launch_bounds__(256) void kout_kernel(const float* __restrict__ state,
                                                   void* __restrict__ out,
                                                   const int* __restrict__ flag){
  int i = blockIdx.x*256 + threadIdx.x;
  if (flag[0]) ((u16*)out)[i] = f2bf(state[i]);
  else         ((float*)out)[i] = state[i];
}

// ---------------- launch ----------------
extern "C" void kernel_launch(void* const* d_in, const int* in_sizes, int n_in,
                              void* d_out, int out_size, void* d_ws, size_t ws_size,
                              hipStream_t stream){
  const void* inp   = d_in[0];
  const void* slots = d_in[1];
  WP wp;
  for (int i = 0; i < 25; i++) wp.p[i] = d_in[2+i];

  u16*   kbuf  = (u16*)d_ws;                         // BN*64 bf16 (k_pos, row-major)
  u16*   vtg   = kbuf + (size_t)BN*64;               // BN*64 bf16 (v_pos, d-major [b][d][n])
  float* w     = (float*)(vtg + (size_t)BN*64);      // fp32 weight arena
  float* state = w + W_TOTAL;                        // 32*8*64
  float* pupd  = state + 16384;                      // 32*32*512 partials
  float* psums = pupd + 524288;                      // 32*32*4*8
  u16*   qf    = (u16*)(psums + 32768);              // 32*2*64*8 bf16 B-frags
  u16*   fkv   = qf + 32768;
  u16*   f1    = fkv + 8192;
  u16*   f2    = f1 + 8192;
  int*   flag  = (int*)(f2 + 8192);

  kdetect_kernel<<<1, 64, 0, stream>>>((const u16*)inp, flag);
  kw_kernel<<<26, 256, 0, stream>>>(wp, w, state, slots, flag);
  kpack_kernel<<<3, 256, 0, stream>>>(wp, fkv, f1, f2, flag);
  k0_kernel<<<8192, 256, 0, stream>>>(inp, w, fkv, f1, f2, kbuf, vtg, flag);
  b1_kernel<<<32, 512, 0, stream>>>(w, state, qf);
  for (int it = 0; it < 3; it++){
    b2_kernel<<<1024, 256, 0, stream>>>(kbuf, vtg, qf, pupd, psums);
    b3q_kernel<<<256, 192, 0, stream>>>(w, state, pupd, psums, qf);
  }
  kout_kernel<<<64, 256, 0, stream>>>(state, d_out, flag);
}

// Round 7
// 488.022 us; speedup vs baseline: 1.1290x; 1.1290x over previous
//
#include <hip/hip_runtime.h>

typedef unsigned short u16;
typedef unsigned int   u32;

#define NN 16384
#define BN 524288      /* B*N = 32*16384 */
#define LN_EPS 1e-5f

typedef __attribute__((ext_vector_type(8))) short bf16x8;
typedef __attribute__((ext_vector_type(4))) float f32x4;
#define MFMA(a,b,c) __builtin_amdgcn_mfma_f32_16x16x32_bf16(a,b,c,0,0,0)

// ---------------- helpers ----------------
__device__ __forceinline__ float bf2f(u16 h){
  union { u32 u; float f; } c; c.u = ((u32)h) << 16; return c.f;
}
__device__ __forceinline__ u16 f2bf(float f){            // RNE (init/output paths)
  union { float f; u32 u; } c; c.f = f;
  u32 r = (c.u + 0x7fffu + ((c.u >> 16) & 1u)) >> 16;
  return (u16)r;
}
__device__ __forceinline__ u16 f2bf_fast(float f){       // round-half-up, 2 VALU ops
  union { float f; u32 u; } c; c.f = f;
  return (u16)((c.u + 0x8000u) >> 16);
}
__device__ __forceinline__ u32 pack2(float a, float b){  // RNE pair
  return (u32)f2bf(a) | ((u32)f2bf(b) << 16);
}
__device__ __forceinline__ u32 pack2f(float a, float b){ // fast pair: add,add,perm
  union { float f; u32 u; } ca, cb; ca.f = a; cb.f = b;
  return ((ca.u + 0x8000u) >> 16) | ((cb.u + 0x8000u) & 0xffff0000u);
}
__device__ __forceinline__ void unpack8(uint4 v, float* o){
  o[0]=bf2f((u16)(v.x&0xffffu)); o[1]=bf2f((u16)(v.x>>16));
  o[2]=bf2f((u16)(v.y&0xffffu)); o[3]=bf2f((u16)(v.y>>16));
  o[4]=bf2f((u16)(v.z&0xffffu)); o[5]=bf2f((u16)(v.z>>16));
  o[6]=bf2f((u16)(v.w&0xffffu)); o[7]=bf2f((u16)(v.w>>16));
}
__device__ __forceinline__ float ldin(const void* p, int i, int isbf){
  return isbf ? bf2f(((const u16*)p)[i]) : ((const float*)p)[i];
}

// ---------------- fp32 weight arena offsets (floats) ----------------
enum {
  O_LNING=0, O_LNINB=64, O_LNSG=128, O_LNSB=192, O_LNMG=256, O_LNMB=320,
  O_WQ=384, O_WK=4480, O_WV=8576,
  O_WIH=12672, O_WHH=24960, O_BIH=37248, O_BHH=37440,
  O_MLPW1=37632, O_MLPB1=45824, O_MLPW2=45952, O_MLPB2=54144,
  O_PAW=54208, O_PAB=54336,
  O_PEG=54400, O_PEB=54464, O_PEW1=54528, O_PEB1=62720, O_PEW2=62848, O_PEB2=71040,
  W_TOTAL=71104
};
__device__ const int g_woff[25] = {O_LNING,O_LNINB,O_LNSG,O_LNSB,O_LNMG,O_LNMB,
  O_WQ,O_WK,O_WV,O_WIH,O_WHH,O_BIH,O_BHH,O_MLPW1,O_MLPB1,O_MLPW2,O_MLPB2,
  O_PAW,O_PAB,O_PEG,O_PEB,O_PEW1,O_PEB1,O_PEW2,O_PEB2};
__device__ const int g_wsz[25]  = {64,64,64,64,64,64,4096,4096,4096,12288,12288,
  192,192,8192,128,8192,64,128,64,64,64,8192,128,8192,64};

struct WP { const void* p[25]; };

__device__ __forceinline__ int detect_isbf(const u16* inp){
  int votes = 0;
  for (int i = 0; i < 64; i++){
    u16 h = inp[2*i];
    int e = (h >> 7) & 0xff;
    int m = h & 0x7f;
    if ((e == 0 && m == 0) || (e >= 100 && e <= 144)) votes++;
  }
  return votes >= 48;
}

// ------- kernel: init (dtype detect + weight arena + state + B-frag packs) -------
__global__ __launch_bounds__(256) void kinit_kernel(WP wp, const u16* __restrict__ inp,
                                                    float* __restrict__ w,
                                                    float* __restrict__ state,
                                                    const void* __restrict__ slots,
                                                    u16* __restrict__ fkv,
                                                    u16* __restrict__ f1,
                                                    u16* __restrict__ f2,
                                                    int* __restrict__ flag){
  __shared__ int sbf;
  if (threadIdx.x == 0){
    int v = detect_isbf(inp);
    sbf = v;
    if (blockIdx.x == 0) flag[0] = v;
  }
  __syncthreads();
  int isbf = sbf;
  int blk = blockIdx.x;
  if (blk < 25){
    const void* src = wp.p[blk];
    int off = g_woff[blk], sz = g_wsz[blk];
    for (int i = threadIdx.x; i < sz; i += 256)
      w[off + i] = ldin(src, i, isbf);
  } else if (blk == 25){
    for (int i = threadIdx.x; i < 512; i += 256){
      float sv = ldin(slots, i, isbf);
      for (int b = 0; b < 32; b++) state[b*512 + i] = sv;
    }
  } else {
    int pk = blk - 26;
    const void* pWk = wp.p[7];  const void* pWv = wp.p[8];
    const void* pW1 = wp.p[21]; const void* pW2 = wp.p[23];
    for (int e = threadIdx.x; e < 8192; e += 256){
      int j = e & 7, lane = (e >> 3) & 63, frag = e >> 9;
      int qd = lane >> 4, l15 = lane & 15;
      if (pk == 0){            // [Wk|Wv]: K=64, N=128, frag = nt*2 + ks
        int nt = frag >> 1, ks = frag & 1;
        int k = ks*32 + qd*8 + j, n = nt*16 + l15;
        float v = (n < 64) ? ldin(pWk, k*64 + n, isbf) : ldin(pWv, k*64 + (n-64), isbf);
        fkv[e] = f2bf(v);
      } else if (pk == 1){     // pe_W1: K=64, N=128
        int nt = frag >> 1, ks = frag & 1;
        int k = ks*32 + qd*8 + j, n = nt*16 + l15;
        f1[e] = f2bf(ldin(pW1, k*128 + n, isbf));
      } else {                 // pe_W2: K=128, N=64, frag = nt*4 + s
        int nt = frag >> 2, s = frag & 3;
        int k = s*32 + qd*8 + j, n = nt*16 + l15;
        f2[e] = f2bf(ldin(pW2, k*64 + n, isbf));
      }
    }
  }
}

// ============== FUSED kernel: LN + [k|v] GEMM + pos-enc MLP (64 rows/block) ==========
// Outputs: kbuf row-major (n x 64), vtg d-major (VT[b][d][n]).
#define KVS 136
__global__ __launch_bounds__(256) void k0_kernel(const void* __restrict__ inpv,
                                                 const float* __restrict__ w,
                                                 const u16* __restrict__ fkv,
                                                 const u16* __restrict__ f1,
                                                 const u16* __restrict__ f2,
                                                 u16* __restrict__ kbuf,
                                                 u16* __restrict__ vtg,
                                                 const int* __restrict__ flag){
  __shared__ __align__(16) u16 shA[5120];     // T1(64x72) -> Hw(4x32x40) -> Vt(64x72)
  __shared__ __align__(16) u16 shB[128*72];   // KV(64xKVS) -> T2(128x72)
  __shared__ float gbuf[128];
  int isbf = flag[0];
  int t = threadIdx.x;
  size_t row0 = (size_t)blockIdx.x * 64;
  int lane = t & 63, wid = t >> 6, qd = lane >> 4, l15 = lane & 15;

  // ---- P1: LN(feats), thread per row (64 rows) ----
  if (t < 64){
    size_t row = row0 + t;
    float x[64], g0, g1;
    if (isbf){
      const u32* up = (const u32*)((const u16*)inpv + row*66);
#pragma unroll
      for (int c = 0; c < 32; c++){
        u32 v = up[c];
        x[2*c] = bf2f((u16)(v & 0xffffu)); x[2*c+1] = bf2f((u16)(v >> 16));
      }
      u32 gv = up[32];
      g0 = bf2f((u16)(gv & 0xffffu)); g1 = bf2f((u16)(gv >> 16));
    } else {
      const float2* fp = (const float2*)((const float*)inpv + row*66);
#pragma unroll
      for (int c = 0; c < 32; c++){ float2 v = fp[c]; x[2*c] = v.x; x[2*c+1] = v.y; }
      float2 gv = fp[32]; g0 = gv.x; g1 = gv.y;
    }
    gbuf[2*t] = g0; gbuf[2*t+1] = g1;
    float mu = 0.f;
#pragma unroll
    for (int i = 0; i < 64; i++) mu += x[i];
    mu *= (1.f/64.f);
    float va = 0.f;
#pragma unroll
    for (int i = 0; i < 64; i++){ x[i] -= mu; va += x[i]*x[i]; }
    va *= (1.f/64.f);
    float rs = rsqrtf(va + LN_EPS);
#pragma unroll
    for (int i = 0; i < 64; i++) x[i] = x[i]*rs*w[O_LNING+i] + w[O_LNINB+i];
#pragma unroll
    for (int c = 0; c < 8; c++){
      uint4 q; q.x = pack2f(x[8*c],x[8*c+1]); q.y = pack2f(x[8*c+2],x[8*c+3]);
      q.z = pack2f(x[8*c+4],x[8*c+5]); q.w = pack2f(x[8*c+6],x[8*c+7]);
      *(uint4*)&shA[t*72 + c*8] = q;
    }
  }
  __syncthreads();

  // ---- P2: [k|v] = T1 @ fkv -> KV in shB ----
  {
    bf16x8 af[2];
#pragma unroll
    for (int ks = 0; ks < 2; ks++)
      af[ks] = *(const bf16x8*)&shA[(wid*16 + l15)*72 + ks*32 + qd*8];
#pragma unroll
    for (int nt = 0; nt < 8; nt++){
      bf16x8 b0 = *(const bf16x8*)(fkv + ((size_t)(nt*2+0)*64 + lane)*8);
      bf16x8 b1 = *(const bf16x8*)(fkv + ((size_t)(nt*2+1)*64 + lane)*8);
      f32x4 acc = {0.f,0.f,0.f,0.f};
      acc = MFMA(af[0], b0, acc);
      acc = MFMA(af[1], b1, acc);
      int rb = wid*16 + qd*4;
#pragma unroll
      for (int r = 0; r < 4; r++) shB[(rb+r)*KVS + nt*16 + l15] = f2bf_fast(acc[r]);
    }
  }
  __syncthreads();

  // ---- P3a: pos-enc LN in regs (128 virtual rows: 0-63 k, 64-127 v) ----
  float tv[64];
  int act = (t < 128);
  if (act){
    int phys = t & 63, isv = (t >> 6) & 1;
    float g0 = gbuf[2*phys], g1 = gbuf[2*phys+1];
    const uint4* rp = (const uint4*)&shB[phys*KVS + isv*64];
#pragma unroll
    for (int c = 0; c < 8; c++){ uint4 q4 = rp[c]; unpack8(q4, &tv[c*8]); }
#pragma unroll
    for (int i = 0; i < 64; i++)
      tv[i] += g0*w[O_PAW+i] + g1*w[O_PAW+64+i] + w[O_PAB+i];
    float mu = 0.f;
#pragma unroll
    for (int i = 0; i < 64; i++) mu += tv[i];
    mu *= (1.f/64.f);
    float va = 0.f;
#pragma unroll
    for (int i = 0; i < 64; i++){ tv[i] -= mu; va += tv[i]*tv[i]; }
    va *= (1.f/64.f);
    float rs = rsqrtf(va + LN_EPS);
#pragma unroll
    for (int i = 0; i < 64; i++) tv[i] = tv[i]*rs*w[O_PEG+i] + w[O_PEB+i];
  }
  __syncthreads();         // KV reads done; shB reusable
  if (act){
#pragma unroll
    for (int c = 0; c < 8; c++){
      uint4 q; q.x = pack2f(tv[8*c],tv[8*c+1]); q.y = pack2f(tv[8*c+2],tv[8*c+3]);
      q.z = pack2f(tv[8*c+4],tv[8*c+5]); q.w = pack2f(tv[8*c+6],tv[8*c+7]);
      *(uint4*)&shB[t*72 + c*8] = q;
    }
  }
  __syncthreads();

  // ---- P4: MLP; wave covers 32 virtual rows ----
  f32x4 out[2][4];
  {
    u16* Hw = shA + wid*1280;                  // 32 rows x 40 u16
    bf16x8 af[2][2];
#pragma unroll
    for (int mt = 0; mt < 2; mt++)
#pragma unroll
      for (int ks = 0; ks < 2; ks++)
        af[mt][ks] = *(const bf16x8*)&shB[(wid*32 + mt*16 + l15)*72 + ks*32 + qd*8];
#pragma unroll
    for (int mt = 0; mt < 2; mt++)
#pragma unroll
      for (int nt = 0; nt < 4; nt++) out[mt][nt] = (f32x4){0.f,0.f,0.f,0.f};

#pragma unroll
    for (int s = 0; s < 4; s++){
#pragma unroll
      for (int e = 0; e < 2; e++){
        int nn = s*2 + e;
        bf16x8 b0 = *(const bf16x8*)(f1 + ((size_t)(nn*2+0)*64 + lane)*8);
        bf16x8 b1 = *(const bf16x8*)(f1 + ((size_t)(nn*2+1)*64 + lane)*8);
        float bias1 = w[O_PEB1 + nn*16 + l15];
#pragma unroll
        for (int mt = 0; mt < 2; mt++){
          f32x4 h = {0.f,0.f,0.f,0.f};
          h = MFMA(af[mt][0], b0, h);
          h = MFMA(af[mt][1], b1, h);
#pragma unroll
          for (int r = 0; r < 4; r++)
            Hw[(mt*16 + qd*4 + r)*40 + e*16 + l15] = f2bf_fast(fmaxf(h[r] + bias1, 0.f));
        }
      }
      bf16x8 a2[2];
#pragma unroll
      for (int mt = 0; mt < 2; mt++)
        a2[mt] = *(const bf16x8*)&Hw[(mt*16 + l15)*40 + qd*8];   // same-wave RAW
#pragma unroll
      for (int nt = 0; nt < 4; nt++){
        bf16x8 bw = *(const bf16x8*)(f2 + ((size_t)(nt*4 + s)*64 + lane)*8);
#pragma unroll
        for (int mt = 0; mt < 2; mt++)
          out[mt][nt] = MFMA(a2[mt], bw, out[mt][nt]);
      }
    }
  }
  __syncthreads();   // all Hw reads done; shA reusable as Vt

  // ---- epilogue: k rows -> global row-major; v rows -> Vt LDS transpose ----
  if (wid < 2){
#pragma unroll
    for (int nt = 0; nt < 4; nt++){
      float b2v = w[O_PEB2 + nt*16 + l15];
#pragma unroll
      for (int mt = 0; mt < 2; mt++){
        size_t rb = row0 + wid*32 + mt*16 + qd*4;
#pragma unroll
        for (int r = 0; r < 4; r++)
          kbuf[(rb+r)*64 + nt*16 + l15] = f2bf_fast(out[mt][nt][r] + b2v);
      }
    }
  } else {
#pragma unroll
    for (int nt = 0; nt < 4; nt++){
      float b2v = w[O_PEB2 + nt*16 + l15];
#pragma unroll
      for (int mt = 0; mt < 2; mt++){
        int vr = (wid-2)*32 + mt*16 + qd*4;
#pragma unroll
        for (int r = 0; r < 4; r++)
          shA[(nt*16 + l15)*72 + vr + r] = f2bf_fast(out[mt][nt][r] + b2v);
      }
    }
  }
  __syncthreads();

  // ---- copy Vt -> vtg [b][d][n] ----
  {
    int d = t >> 2, c = t & 3;
    int b  = (int)(row0 >> 14);
    int nl = (int)(row0 & 16383);
    uint4 v0 = *(const uint4*)&shA[d*72 + c*16];
    uint4 v1 = *(const uint4*)&shA[d*72 + c*16 + 8];
    u16* dst = vtg + (size_t)b*1048576 + (size_t)d*NN + nl + c*16;
    *(uint4*)dst = v0;
    *(uint4*)(dst + 8) = v1;
  }
}

// ---------------- kernel: initial q = 0.125*LN(state)@Wq -> qf (MFMA B-frag) -----
__global__ __launch_bounds__(512) void b1_kernel(const float* __restrict__ w,
                                                 const float* __restrict__ state,
                                                 u16* __restrict__ qf){
  __shared__ float qrow[8*64];
  int b = blockIdx.x, t = threadIdx.x;
  int s = t >> 6, lane = t & 63;
  float xv = state[(b*8+s)*64 + lane];
  float sum = xv;
#pragma unroll
  for (int off = 32; off; off >>= 1) sum += __shfl_xor(sum, off, 64);
  float mu = sum * (1.f/64.f);
  float xc = xv - mu;
  float ss = xc*xc;
#pragma unroll
  for (int off = 32; off; off >>= 1) ss += __shfl_xor(ss, off, 64);
  float rs = rsqrtf(ss*(1.f/64.f) + LN_EPS);
  float xln = xc*rs*w[O_LNSG+lane] + w[O_LNSB+lane];
  float acc = 0.f;
#pragma unroll
  for (int i = 0; i < 64; i++){
    float xi = __shfl(xln, i, 64);
    acc += xi * w[O_WQ + i*64 + lane];
  }
  qrow[s*64 + lane] = acc * 0.125f;          // fold D^-0.5
  __syncthreads();
  if (t < 128){
    int ks = t >> 6, ln = t & 63, ql = ln & 15, qq = ln >> 4;
    u32 pk[4];
#pragma unroll
    for (int jp = 0; jp < 4; jp++){
      float v0 = (ql < 8) ? qrow[ql*64 + ks*32 + qq*8 + 2*jp]     : 0.f;
      float v1 = (ql < 8) ? qrow[ql*64 + ks*32 + qq*8 + 2*jp + 1] : 0.f;
      pk[jp] = pack2(v0, v1);
    }
    *(uint4*)(qf + ((size_t)(b*2+ks)*64 + ln)*8) = *(uint4*)pk;
  }
}

// ---------------- kernel: attention (MFMA QK + softmax + MFMA PV), 512 n/block ----
#define PMS 520
__global__ __launch_bounds__(256) void b2_kernel(const u16* __restrict__ kbuf,
                                                 const u16* __restrict__ vtg,
                                                 const u16* __restrict__ qf,
                                                 float* __restrict__ pupd,
                                                 float* __restrict__ psums){
  __shared__ __align__(16) u16 pm[8*PMS];        // P, bf16 (8 slot rows, padded)
  int t = threadIdx.x, lane = t & 63, wid = t >> 6, l15 = lane & 15, quad = lane >> 4;
  int b = blockIdx.x >> 5, chunk = blockIdx.x & 31;
  size_t gn0 = (size_t)b*NN + (size_t)chunk*512;

  bf16x8 q0 = *(const bf16x8*)(qf + ((size_t)(b*2+0)*64 + lane)*8);
  bf16x8 q1 = *(const bf16x8*)(qf + ((size_t)(b*2+1)*64 + lane)*8);

  float psum = 0.f;
  int wbase = wid*128;
#pragma unroll
  for (int mt = 0; mt < 8; mt++){
    const u16* kp = kbuf + (gn0 + wbase + mt*16 + l15)*64;
    bf16x8 a0 = *(const bf16x8*)(kp + quad*8);
    bf16x8 a1 = *(const bf16x8*)(kp + 32 + quad*8);
    f32x4 dg = {0.f,0.f,0.f,0.f};
    dg = MFMA(a0, q0, dg);
    dg = MFMA(a1, q1, dg);
#pragma unroll
    for (int r = 0; r < 4; r++){
      float lg = fminf(dg[r], 40.f);           // softmax w/o max-sub (clamped)
      float ex = __expf(lg);
      float es = ex;
      es += __shfl_xor(es, 1, 64);
      es += __shfl_xor(es, 2, 64);
      es += __shfl_xor(es, 4, 64);
      float p = __fdividef(ex, es) + 1e-8f;
      psum += p;
      if (l15 < 8){
        int n = wbase + mt*16 + quad*4 + r;
        pm[l15*PMS + n] = f2bf_fast(p);
      }
    }
  }
  psum += __shfl_xor(psum, 16, 64);
  psum += __shfl_xor(psum, 32, 64);
  if (quad == 0 && l15 < 8)
    psums[(size_t)((b*32+chunk)*4 + wid)*8 + l15] = psum;
  __syncthreads();

  // PV swapped: A = VT rows (m=d), B = P^T (col=s; cols 8..15 garbage, ignored)
  f32x4 acc = {0.f,0.f,0.f,0.f};
  const u16* vp  = vtg + (size_t)b*1048576 + (size_t)(wid*16 + l15)*NN
                       + (size_t)chunk*512 + quad*8;
  const u16* pmr = pm + (l15 & 7)*PMS + quad*8;
#pragma unroll
  for (int ks = 0; ks < 16; ks++){
    bf16x8 va = *(const bf16x8*)(vp + ks*32);
    bf16x8 pb = *(const bf16x8*)(pmr + ks*32);
    acc = MFMA(va, pb, acc);
  }
  if (l15 < 8){
    float4 st = { acc[0], acc[1], acc[2], acc[3] };   // 4 consecutive d
    *(float4*)(pupd + (size_t)(b*32+chunk)*512 + l15*64 + wid*16 + quad*4) = st;
  }
}

// ------- kernel: partial-reduce + GRU + MLP + next-q, one block per (b,s) --------
__global__ __launch_bounds__(192) void b3q_kernel(const float* __restrict__ w,
                                                  float* __restrict__ state,
                                                  const float* __restrict__ pupd,
                                                  const float* __restrict__ psums,
                                                  u16* __restrict__ qf){
  __shared__ float uL[64], pv[64], hL[64], hln[64], gx[192], gh[192], hid[128], red[128], qs[64];
  __shared__ float ssum;
  int bs = blockIdx.x, b = bs >> 3, s = bs & 7, t = threadIdx.x;

  if (t < 64){
    float a = 0.f;
    const float* pp = pupd + (size_t)b*32*512 + s*64 + t;
#pragma unroll 4
    for (int c = 0; c < 32; c++) a += pp[(size_t)c*512];
    uL[t] = a;
    pv[t] = state[(b*8+s)*64 + t];
  } else {
    int i = t - 64;    // 128 (chunk,wave) partial sums
    red[i] = psums[(size_t)(b*128 + i)*8 + s];
  }
  __syncthreads();
  if (t < 64){
    float a = red[t] + red[t + 64];
#pragma unroll
    for (int off = 32; off; off >>= 1) a += __shfl_xor(a, off, 64);
    if (t == 0) ssum = a;
  }
  __syncthreads();

  { // gx, gh (j = t, 192 threads); fold 1/ssum into gx linear term
    float inv = 1.f/ssum;
    int j = t;
    float x0=0.f,x1=0.f,x2=0.f,x3=0.f, y0=0.f,y1=0.f,y2=0.f,y3=0.f;
#pragma unroll 4
    for (int d = 0; d < 64; d += 4){
      x0 += uL[d]  *w[O_WIH + (d)*192 + j];   y0 += pv[d]  *w[O_WHH + (d)*192 + j];
      x1 += uL[d+1]*w[O_WIH + (d+1)*192 + j]; y1 += pv[d+1]*w[O_WHH + (d+1)*192 + j];
      x2 += uL[d+2]*w[O_WIH + (d+2)*192 + j]; y2 += pv[d+2]*w[O_WHH + (d+2)*192 + j];
      x3 += uL[d+3]*w[O_WIH + (d+3)*192 + j]; y3 += pv[d+3]*w[O_WHH + (d+3)*192 + j];
    }
    gx[j] = w[O_BIH + j] + (x0+x1+x2+x3)*inv;
    gh[j] = w[O_BHH + j] + (y0+y1+y2+y3);
  }
  __syncthreads();

  if (t < 64){
    int d = t;
    float r = 1.f/(1.f + expf(-(gx[d]      + gh[d])));
    float z = 1.f/(1.f + expf(-(gx[64+d]   + gh[64+d])));
    float nv = tanhf(gx[128+d] + r*gh[128+d]);
    hL[d] = (1.f - z)*nv + z*pv[d];
  }
  __syncthreads();

  if (t < 64){
    float h = hL[t];
    float sum = h;
#pragma unroll
    for (int off = 32; off; off >>= 1) sum += __shfl_xor(sum, off, 64);
    float mu = sum * (1.f/64.f);
    float xc = h - mu;
    float ss2 = xc*xc;
#pragma unroll
    for (int off = 32; off; off >>= 1) ss2 += __shfl_xor(ss2, off, 64);
    float rs = rsqrtf(ss2*(1.f/64.f) + LN_EPS);
    hln[t] = xc*rs*w[O_LNMG+t] + w[O_LNMB+t];
  }
  __syncthreads();

  if (t < 128){
    int j = t;
    float a0=0.f,a1=0.f,a2v=0.f,a3=0.f;
#pragma unroll 4
    for (int d = 0; d < 64; d += 4){
      a0  += hln[d]  *w[O_MLPW1 + (d)*128 + j];
      a1  += hln[d+1]*w[O_MLPW1 + (d+1)*128 + j];
      a2v += hln[d+2]*w[O_MLPW1 + (d+2)*128 + j];
      a3  += hln[d+3]*w[O_MLPW1 + (d+3)*128 + j];
    }
    hid[j] = fmaxf(a0+a1+a2v+a3 + w[O_MLPB1 + j], 0.f);
  }
  __syncthreads();

  if (t < 64){
    int d = t;
    float o0=0.f,o1=0.f,o2=0.f,o3=0.f;
#pragma unroll 4
    for (int j = 0; j < 128; j += 4){
      o0 += hid[j]  *w[O_MLPW2 + (j)*64 + d];
      o1 += hid[j+1]*w[O_MLPW2 + (j+1)*64 + d];
      o2 += hid[j+2]*w[O_MLPW2 + (j+2)*64 + d];
      o3 += hid[j+3]*w[O_MLPW2 + (j+3)*64 + d];
    }
    float sv = hL[d] + o0+o1+o2+o3 + w[O_MLPB2 + d];
    state[(b*8+s)*64 + d] = sv;

    // ---- next iteration's q row for this (b,s): 0.125 * LN(sv) @ Wq ----
    float sum = sv;
#pragma unroll
    for (int off = 32; off; off >>= 1) sum += __shfl_xor(sum, off, 64);
    float mu = sum * (1.f/64.f);
    float xc = sv - mu;
    float ss2 = xc*xc;
#pragma unroll
    for (int off = 32; off; off >>= 1) ss2 += __shfl_xor(ss2, off, 64);
    float rs = rsqrtf(ss2*(1.f/64.f) + LN_EPS);
    float xln = xc*rs*w[O_LNSG+d] + w[O_LNSB+d];
    float q = 0.f;
#pragma unroll
    for (int i = 0; i < 64; i++){
      float xi = __shfl(xln, i, 64);
      q += xi * w[O_WQ + i*64 + d];
    }
    qs[d] = q * 0.125f;
  }
  __syncthreads();

  if (t < 32){   // scatter this s's slice of the qf B-frag pack
    int ks = t >> 4, qq = (t >> 2) & 3, jp = t & 3;
    u32 v = pack2f(qs[ks*32 + qq*8 + 2*jp], qs[ks*32 + qq*8 + 2*jp + 1]);
    *(u32*)(qf + ((size_t)((b*2+ks)*64) + qq*16 + s)*8 + jp*2) = v;
  }
}

// ---------------- kernel: state (fp32) -> out (bf16 or fp32 per flag) ----------------
__global__ __launch_bounds__(256) void kout_kernel(const float* __restrict__ state,
                                                   void* __restrict__ out,
                                                   const int* __restrict__ flag){
  int i = blockIdx.x*256 + threadIdx.x;
  if (flag[0]) ((u16*)out)[i] = f2bf(state[i]);
  else         ((float*)out)[i] = state[i];
}

// ---------------- launch ----------------
extern "C" void kernel_launch(void* const* d_in, const int* in_sizes, int n_in,
                              void* d_out, int out_size, void* d_ws, size_t ws_size,
                              hipStream_t stream){
  const void* inp   = d_in[0];
  const void* slots = d_in[1];
  WP wp;
  for (int i = 0; i < 25; i++) wp.p[i] = d_in[2+i];

  u16*   kbuf  = (u16*)d_ws;                         // BN*64 bf16 (k_pos, row-major)
  u16*   vtg   = kbuf + (size_t)BN*64;               // BN*64 bf16 (v_pos, d-major [b][d][n])
  float* w     = (float*)(vtg + (size_t)BN*64);      // fp32 weight arena
  float* state = w + W_TOTAL;                        // 32*8*64
  float* pupd  = state + 16384;                      // 32*32*512 partials
  float* psums = pupd + 524288;                      // 32*32*4*8
  u16*   qf    = (u16*)(psums + 32768);              // 32*2*64*8 bf16 B-frags
  u16*   fkv   = qf + 32768;
  u16*   f1    = fkv + 8192;
  u16*   f2    = f1 + 8192;
  int*   flag  = (int*)(f2 + 8192);

  kinit_kernel<<<29, 256, 0, stream>>>(wp, (const u16*)inp, w, state, slots, fkv, f1, f2, flag);
  k0_kernel<<<8192, 256, 0, stream>>>(inp, w, fkv, f1, f2, kbuf, vtg, flag);
  b1_kernel<<<32, 512, 0, stream>>>(w, state, qf);
  for (int it = 0; it < 3; it++){
    b2_kernel<<<1024, 256, 0, stream>>>(kbuf, vtg, qf, pupd, psums);
    b3q_kernel<<<256, 192, 0, stream>>>(w, state, pupd, psums, qf);
  }
  kout_kernel<<<64, 256, 0, stream>>>(state, d_out, flag);
}